// Round 2
// baseline (19003.143 us; speedup 1.0000x reference)
//
#include <hip/hip_runtime.h>
#include <math.h>

// Problem constants (GPT reference)
#define V_  32000
#define D_  512
#define H_  8
#define DH_ 64
#define L_  8
#define FF_ 2048
#define B_  2
#define T_  2048
#define M_  (B_*T_)   // 4096 token rows

// ---------------------------------------------------------------------------
// Embedding + positional encoding: h[row,d] = emb[x[row],d] + pe(t,d), fp32
// ---------------------------------------------------------------------------
__global__ void embed_pe_kernel(const int* __restrict__ x,
                                const float* __restrict__ emb,
                                float* __restrict__ h) {
    int row = blockIdx.x;          // 0..M_-1 ; row = b*T + t
    int t   = row % T_;
    int tok = x[row];
    const float* er = emb + (size_t)tok * D_;
    for (int d = threadIdx.x; d < D_; d += blockDim.x) {
        int i = d >> 1;
        // div_i = 10000^(-2i/D)
        float freq = expf((float)(2 * i) * (-9.210340371976184f / (float)D_));
        float ang  = (float)t * freq;
        float pe   = (d & 1) ? cosf(ang) : sinf(ang);
        h[(size_t)row * D_ + d] = er[d] + pe;
    }
}

// ---------------------------------------------------------------------------
// LayerNorm: one wave (64 lanes) per row of D=512. fp32 in, fp32 out.
// ---------------------------------------------------------------------------
__global__ __launch_bounds__(64)
void layernorm_kernel(const float* __restrict__ xin,
                      const float* __restrict__ scale,
                      const float* __restrict__ bias,
                      float* __restrict__ yout) {
    int row  = blockIdx.x;
    int lane = threadIdx.x;        // 0..63
    const float* xr = xin + (size_t)row * D_;
    float v[8];
    float s = 0.f;
#pragma unroll
    for (int i = 0; i < 8; i++) { v[i] = xr[i * 64 + lane]; s += v[i]; }
#pragma unroll
    for (int off = 32; off; off >>= 1) s += __shfl_xor(s, off, 64);
    float mu = s * (1.0f / D_);
    float var = 0.f;
#pragma unroll
    for (int i = 0; i < 8; i++) { float d0 = v[i] - mu; var += d0 * d0; }
#pragma unroll
    for (int off = 32; off; off >>= 1) var += __shfl_xor(var, off, 64);
    var *= (1.0f / D_);
    float r = rsqrtf(var + 1e-5f);
    float* yr = yout + (size_t)row * D_;
#pragma unroll
    for (int i = 0; i < 8; i++) {
        int d0 = i * 64 + lane;
        yr[d0] = (v[i] - mu) * r * scale[d0] + bias[d0];
    }
}

// ---------------------------------------------------------------------------
// Generic tiled fp32 GEMM: C[M,N] = A[M,K] @ W[K,N] + bias, epilogue flags.
// BM=BN=64, BK=16, 256 threads, 4x4 per thread. M,N,K multiples of tiles.
// ---------------------------------------------------------------------------
#define BM 64
#define BN 64
#define BK 16
#define F_GELU  1
#define F_RES   2

__global__ __launch_bounds__(256)
void gemm_kernel(const float* __restrict__ A,    // [M_,K] fp32
                 const float* __restrict__ W,    // [K,N]  fp32
                 const float* __restrict__ bias, // [N]
                 const float* __restrict__ res,  // [M_,N] or null
                 float* __restrict__ C,          // fp32 out
                 int N, int K, int flags) {
    __shared__ float As[BM][BK + 1];   // +1 pad: breaks bank conflicts on a[] reads
    __shared__ float Bs[BK][BN];
    int m0 = blockIdx.y * BM;
    int n0 = blockIdx.x * BN;
    int tid = threadIdx.x;
    int tx = tid & 15, ty = tid >> 4;

    float acc[4][4] = {};
    for (int k0 = 0; k0 < K; k0 += BK) {
        // A tile 64x16: ak fastest across tid -> coalesced 64B runs
#pragma unroll
        for (int i = 0; i < 4; i++) {
            int e  = tid + i * 256;
            int am = e >> 4, ak = e & 15;
            As[am][ak] = A[(size_t)(m0 + am) * K + (k0 + ak)];
        }
        // B tile 16x64: bn fastest -> coalesced rows
#pragma unroll
        for (int i = 0; i < 4; i++) {
            int e  = tid + i * 256;
            int bk = e >> 6, bn = e & 63;
            Bs[bk][bn] = W[(size_t)(k0 + bk) * N + (n0 + bn)];
        }
        __syncthreads();
#pragma unroll
        for (int k = 0; k < BK; k++) {
            float a[4], bb[4];
#pragma unroll
            for (int i = 0; i < 4; i++) a[i] = As[ty * 4 + i][k];
#pragma unroll
            for (int j = 0; j < 4; j++) bb[j] = Bs[k][tx * 4 + j];
#pragma unroll
            for (int i = 0; i < 4; i++)
#pragma unroll
                for (int j = 0; j < 4; j++)
                    acc[i][j] += a[i] * bb[j];
        }
        __syncthreads();
    }

#pragma unroll
    for (int i = 0; i < 4; i++) {
        int m = m0 + ty * 4 + i;
#pragma unroll
        for (int j = 0; j < 4; j++) {
            int n = n0 + tx * 4 + j;
            float c = acc[i][j] + bias[n];
            if (flags & F_GELU) c = 0.5f * c * (1.0f + erff(c * 0.7071067811865476f));
            if (flags & F_RES)  c += res[(size_t)m * N + n];
            C[(size_t)m * N + n] = c;
        }
    }
}

// ---------------------------------------------------------------------------
// Causal flash attention. qkv: [B,T,3D] fp32, layout q|k|v, head-major in D.
// One wave per (b, head, 64-row q tile). q & o accumulator in registers,
// K/V tiles in LDS (broadcast reads), per-key online softmax.
// out: [B,T,D] fp32 at (row*D + head*64 + d)  (== transpose-back layout)
// ---------------------------------------------------------------------------
__global__ __launch_bounds__(64)
void flash_attn_kernel(const float* __restrict__ qkv, float* __restrict__ out) {
    int qt = blockIdx.x;               // q tile (64 rows)
    int bh = blockIdx.y;               // b*H + head
    int b  = bh / H_, hd = bh % H_;
    int lane = threadIdx.x;
    int qi = qt * 64 + lane;           // this lane's query row (within T)

    const float* base = qkv + (size_t)b * T_ * 3 * D_;
    float q[64], o[64];
    const float* qrow = base + (size_t)qi * 3 * D_ + hd * 64;
#pragma unroll
    for (int k = 0; k < 64; k++) { q[k] = qrow[k]; o[k] = 0.f; }

    float m = -1e30f, l = 0.f;
    __shared__ float Ks[64][64];
    __shared__ float Vs[64][64];

    for (int kt = 0; kt <= qt; kt++) {
        __syncthreads();
        for (int j = 0; j < 64; j++) {
            size_t krow = (size_t)(kt * 64 + j) * 3 * D_ + hd * 64;
            Ks[j][lane] = base[krow + D_ + lane];
            Vs[j][lane] = base[krow + 2 * D_ + lane];
        }
        __syncthreads();
        for (int j = 0; j < 64; j++) {
            int kj = kt * 64 + j;
            if (kj > qi) break;        // causal: keys are in order
            float s = 0.f;
#pragma unroll
            for (int k = 0; k < 64; k++) s += q[k] * Ks[j][k];
            s *= 0.125f;               // 1/sqrt(64)
            float mn = fmaxf(m, s);
            float alpha = __expf(m - mn);
            float p     = __expf(s - mn);
            l = l * alpha + p;
#pragma unroll
            for (int k = 0; k < 64; k++) o[k] = o[k] * alpha + p * Vs[j][k];
            m = mn;
        }
    }
    float inv = 1.0f / l;
    float* orow = out + (size_t)(b * T_ + qi) * D_ + hd * 64;
#pragma unroll
    for (int k = 0; k < 64; k++) orow[k] = o[k] * inv;
}

// ---------------------------------------------------------------------------
extern "C" void kernel_launch(void* const* d_in, const int* in_sizes, int n_in,
                              void* d_out, int out_size, void* d_ws, size_t ws_size,
                              hipStream_t stream) {
    const int*   x    = (const int*)   d_in[0];
    const float* emb  = (const float*) d_in[1];
    const float* ln1s = (const float*) d_in[2];
    const float* ln1b = (const float*) d_in[3];
    const float* qkvw = (const float*) d_in[4];
    const float* qkvb = (const float*) d_in[5];
    const float* afw  = (const float*) d_in[6];
    const float* afb  = (const float*) d_in[7];
    const float* ln2s = (const float*) d_in[8];
    const float* ln2b = (const float*) d_in[9];
    const float* fw1  = (const float*) d_in[10];
    const float* fb1  = (const float*) d_in[11];
    const float* fw2  = (const float*) d_in[12];
    const float* fb2  = (const float*) d_in[13];
    const float* lnfs = (const float*) d_in[14];
    const float* lnfb = (const float*) d_in[15];
    const float* fcw  = (const float*) d_in[16];
    const float* fcb  = (const float*) d_in[17];
    float* out = (float*)d_out;

    // fp32 workspace layout (~50 MB).
    // ff [M,2048] aliases att+qkv (both dead when FFN runs): 512+1536 = 2048.
    float* h   = (float*)d_ws;                 // [M_, D_]
    float* y   = h   + (size_t)M_ * D_;        // [M_, D_]
    float* att = y   + (size_t)M_ * D_;        // [M_, D_]
    float* qkv = att + (size_t)M_ * D_;        // [M_, 3*D_]
    float* ff  = att;                          // [M_, FF_] == att..qkv span

    embed_pe_kernel<<<M_, 128, 0, stream>>>(x, emb, h);

    for (int l = 0; l < L_; l++) {
        layernorm_kernel<<<M_, 64, 0, stream>>>(h, ln1s + l * D_, ln1b + l * D_, y);
        gemm_kernel<<<dim3(3 * D_ / BN, M_ / BM), 256, 0, stream>>>(
            y, qkvw + (size_t)l * D_ * 3 * D_, qkvb + l * 3 * D_,
            nullptr, qkv, 3 * D_, D_, 0);
        flash_attn_kernel<<<dim3(T_ / 64, B_ * H_), 64, 0, stream>>>(qkv, att);
        gemm_kernel<<<dim3(D_ / BN, M_ / BM), 256, 0, stream>>>(
            att, afw + (size_t)l * D_ * D_, afb + l * D_,
            h, h, D_, D_, F_RES);
        layernorm_kernel<<<M_, 64, 0, stream>>>(h, ln2s + l * D_, ln2b + l * D_, y);
        gemm_kernel<<<dim3(FF_ / BN, M_ / BM), 256, 0, stream>>>(
            y, fw1 + (size_t)l * D_ * FF_, fb1 + l * FF_,
            nullptr, ff, FF_, D_, F_GELU);
        gemm_kernel<<<dim3(D_ / BN, M_ / BM), 256, 0, stream>>>(
            ff, fw2 + (size_t)l * FF_ * D_, fb2 + l * D_,
            h, h, D_, FF_, F_RES);
    }

    layernorm_kernel<<<M_, 64, 0, stream>>>(h, lnfs, lnfb, y);
    gemm_kernel<<<dim3(V_ / BN, M_ / BM), 256, 0, stream>>>(
        y, fcw, fcb, nullptr, out, V_, D_, 0);
}